// Round 1
// 269.050 us; speedup vs baseline: 1.0364x; 1.0364x over previous
//
#include <hip/hip_runtime.h>
#include <math.h>

typedef __bf16 bf16_t;
typedef __bf16 bf16x8 __attribute__((ext_vector_type(8)));
typedef __bf16 bf16x4 __attribute__((ext_vector_type(4)));
typedef float f32x4 __attribute__((ext_vector_type(4)));

#define MFMA16(a, b, c) __builtin_amdgcn_mfma_f32_16x16x32_bf16((a), (b), (c), 0, 0, 0)

constexpr int Bc = 2, Nc = 2048, Dc = 1024, Hc = 16, HDc = 64;
constexpr float C1 = 0.18033688011112042f;     // 0.125 * log2(e), folded into Q at qkv epilogue
constexpr float LOG2E = 1.4426950408889634f;

// async global->LDS, 16B per lane; LDS base must be wave-uniform (HW adds lane*16)
__device__ __forceinline__ void glds16(const bf16_t* g, bf16_t* l) {
    __builtin_amdgcn_global_load_lds(
        (const __attribute__((address_space(1))) unsigned int*)g,
        (__attribute__((address_space(3))) unsigned int*)l, 16, 0, 0);
}

// ---------------------------------------------------------------------------
__global__ __launch_bounds__(256) void f2b(const float* __restrict__ src,
                                           bf16_t* __restrict__ dst) {
    int i = (blockIdx.x * 256 + threadIdx.x) * 4;
    float4 v = *(const float4*)(src + i);
    bf16x4 o = { (bf16_t)v.x, (bf16_t)v.y, (bf16_t)v.z, (bf16_t)v.w };
    *(bf16x4*)(dst + i) = o;
}

// ---------------------------------------------------------------------------
__global__ __launch_bounds__(256) void tr64(const float* __restrict__ src,
                                            bf16_t* __restrict__ dst, int R, int C) {
    __shared__ bf16_t tile[64 * 66];
    int r0 = blockIdx.y * 64, c0 = blockIdx.x * 64;
    int t = threadIdx.x;
    int cl = t & 63, rl = t >> 6;
#pragma unroll
    for (int p = 0; p < 16; ++p) {
        int r = p * 4 + rl;
        tile[r * 66 + cl] = (bf16_t)src[(size_t)(r0 + r) * C + c0 + cl];
    }
    __syncthreads();
#pragma unroll
    for (int p = 0; p < 16; ++p) {
        int r = p * 4 + rl;
        dst[(size_t)(c0 + r) * R + r0 + cl] = tile[cl * 66 + r];
    }
}

// ---------------------------------------------------------------------------
// 256 blocks: b = blk>>7, 16 rows per block
__global__ __launch_bounds__(256) void pool_partial(const float* __restrict__ x,
                                                    float* __restrict__ pooled) {
    int blk = blockIdx.x;
    int b = blk >> 7, ch = blk & 127;
    int t = threadIdx.x;
    int c = t * 4;
    float s0 = 0.f, s1 = 0.f, s2 = 0.f, s3 = 0.f;
    for (int rr = 0; rr < 16; ++rr) {
        float4 v = *(const float4*)(x + (size_t)(b * Nc + ch * 16 + rr) * Dc + c);
        s0 += v.x; s1 += v.y; s2 += v.z; s3 += v.w;
    }
    atomicAdd(&pooled[b * Dc + c + 0], s0);
    atomicAdd(&pooled[b * Dc + c + 1], s1);
    atomicAdd(&pooled[b * Dc + c + 2], s2);
    atomicAdd(&pooled[b * Dc + c + 3], s3);
}

// ---------------------------------------------------------------------------
// Gate MLP stage 1, parallel: one block per (b, j). hacc[b] += silu(h_j)*w_fg2[j]
__global__ __launch_bounds__(256) void gate1(const float* __restrict__ pooled,
                                             const float* __restrict__ w_fg1,
                                             const float* __restrict__ b_fg1,
                                             const float* __restrict__ w_fg2,
                                             float* __restrict__ hacc) {
    int b = blockIdx.x >> 8, j = blockIdx.x & 255;
    int t = threadIdx.x;
    float p = 0.f;
#pragma unroll
    for (int i = 0; i < 4; ++i) {
        int d = t * 4 + i;
        p += pooled[b * 1024 + d] * w_fg1[d * 256 + j];
    }
#pragma unroll
    for (int off = 32; off > 0; off >>= 1) p += __shfl_down(p, off);
    __shared__ float red[4];
    if ((t & 63) == 0) red[t >> 6] = p;
    __syncthreads();
    if (t == 0) {
        float hj = (red[0] + red[1] + red[2] + red[3]) * (1.0f / 2048.0f) + b_fg1[j];
        hj = hj / (1.0f + __expf(-hj)); // silu
        atomicAdd(&hacc[b], hj * w_fg2[j]);
    }
}

// ---------------------------------------------------------------------------
// biasbuf[b][h][n] = log2(e) * sigmoid(hacc[b]+b_fg2) * (silu(cov*w_ce1+b_ce1) @ w_ce2 + b_ce2)
__global__ __launch_bounds__(256) void covbias_k(const float* __restrict__ coverage,
                                                 const float* __restrict__ w_ce1,
                                                 const float* __restrict__ b_ce1,
                                                 const float* __restrict__ w_ce2,
                                                 const float* __restrict__ b_ce2,
                                                 const float* __restrict__ hacc,
                                                 const float* __restrict__ b_fg2,
                                                 float* __restrict__ biasbuf) {
    int t = threadIdx.x;
    int h = t & 15;
    int gn = blockIdx.x * 16 + (t >> 4);
    int b = gn >> 11, n = gn & 2047;
    float g = 1.0f / (1.0f + __expf(-(hacc[b] + b_fg2[0])));
    float c = coverage[gn];
    float acc = b_ce2[h];
    for (int j = 0; j < 256; ++j) {
        float tv = c * w_ce1[j] + b_ce1[j];
        tv = tv / (1.0f + __expf(-tv));
        acc += tv * w_ce2[j * 16 + h];
    }
    biasbuf[((size_t)b * 16 + h) * 2048 + n] = LOG2E * g * acc;
}

// ---------------------------------------------------------------------------
// QKV GEMM, transposed orientation: D[m=ncol][n=xrow] = Wt-row . X-row.
// Q gets pre-scaled by C1 = 0.125*log2(e) so attn can use exp2 with no FMA.
__global__ __launch_bounds__(256) void qkv_gemm(const bf16_t* __restrict__ Xb,
                                                const bf16_t* __restrict__ Wt,
                                                bf16_t* __restrict__ Q,
                                                bf16_t* __restrict__ Kb,
                                                bf16_t* __restrict__ Vt) {
    __shared__ __align__(16) bf16_t At[128 * 32];
    __shared__ __align__(16) bf16_t Bt[128 * 32];
    int t = threadIdx.x, w = t >> 6, lane = t & 63;
    int l16 = lane & 15, quad = lane >> 4;
    int wm = w & 1, wx = w >> 1;
    int m0 = blockIdx.x * 128;
    int n0 = blockIdx.y * 128;
    f32x4 acc[4][4] = {};
    int sw = (l16 >> 2) & 3;

    for (int k0 = 0; k0 < 1024; k0 += 32) {
#pragma unroll
        for (int i = 0; i < 2; ++i) {
            int fb = i * 4096 + w * 1024;
            int f = fb + lane * 16;
            int row = f >> 6;
            int ch = (f >> 4) & 3;
            int sc = ch ^ ((row >> 2) & 3);
            glds16(Wt + (size_t)(n0 + row) * 1024 + k0 + sc * 8, At + (fb >> 1));
            glds16(Xb + (size_t)(m0 + row) * 1024 + k0 + sc * 8, Bt + (fb >> 1));
        }
        __syncthreads();
        bf16x8 afr[4], bfr[4];
#pragma unroll
        for (int mi = 0; mi < 4; ++mi)
            afr[mi] = *(const bf16x8*)(At + (wm * 64 + mi * 16 + l16) * 32 + ((quad ^ sw) * 8));
#pragma unroll
        for (int ni = 0; ni < 4; ++ni)
            bfr[ni] = *(const bf16x8*)(Bt + (wx * 64 + ni * 16 + l16) * 32 + ((quad ^ sw) * 8));
#pragma unroll
        for (int mi = 0; mi < 4; ++mi)
#pragma unroll
            for (int ni = 0; ni < 4; ++ni)
                acc[mi][ni] = MFMA16(afr[mi], bfr[ni], acc[mi][ni]);
        __syncthreads();
    }

    int sec = n0 >> 10;
    float scq = (sec == 0) ? C1 : 1.0f;
#pragma unroll
    for (int mi = 0; mi < 4; ++mi) {
        int gc = n0 + wm * 64 + mi * 16 + quad * 4;
        int dcol = gc & 1023;
        int h = dcol >> 6, hd = dcol & 63;
#pragma unroll
        for (int ni = 0; ni < 4; ++ni) {
            int gx = m0 + wx * 64 + ni * 16 + l16;
            int b = gx >> 11, n = gx & 2047;
            size_t bh = (size_t)(b * 16 + h);
            if (sec == 2) {
#pragma unroll
                for (int r = 0; r < 4; ++r)
                    Vt[(bh * 64 + hd + r) * 2048 + n] = (bf16_t)acc[mi][ni][r];
            } else {
                bf16x4 pk = { (bf16_t)(acc[mi][ni][0] * scq), (bf16_t)(acc[mi][ni][1] * scq),
                              (bf16_t)(acc[mi][ni][2] * scq), (bf16_t)(acc[mi][ni][3] * scq) };
                bf16_t* dst = (sec == 0 ? Q : Kb);
                *(bf16x4*)(dst + (bh * 2048 + n) * 64 + hd) = pk;
            }
        }
    }
}

// ---------------------------------------------------------------------------
// Flash attention v4: 4 waves x 32 q = 128 q/block, grid (16, 32).
//  - 32 q rows per wave: K/V LDS fragments + bias loads reused for 2 q-tiles
//    (halves LDS read bytes and V-read bank conflicts per score).
//  - bias injected as MFMA accumulator init (Q pre-scaled by C1 in qkv_gemm),
//    so P = exp2(s) directly: no per-score FMA.
//  - softmax denominator via ones-vector MFMA into lacc (MFMA pipe is idle,
//    VALU is the bottleneck); kills 32 adds/iter + the epilogue shuffle tree.
__global__ __launch_bounds__(256) void attn_k(const bf16_t* __restrict__ Q,
                                              const bf16_t* __restrict__ Kb,
                                              const bf16_t* __restrict__ Vt,
                                              const float* __restrict__ biasbuf,
                                              bf16_t* __restrict__ O) {
    __shared__ __align__(16) bf16_t kbuf[2][64 * 64];
    __shared__ __align__(16) bf16_t vbuf[2][64 * 64];
    int t = threadIdx.x, w = t >> 6, lane = t & 63;
    int l16 = lane & 15, quad = lane >> 4;
    int bh = blockIdx.y;
    int b = bh >> 4, h = bh & 15;
    int qa = blockIdx.x * 128 + w * 32;
    const bf16_t* Qh = Q + (size_t)bh * 2048 * 64;
    const bf16_t* Kh = Kb + (size_t)bh * 2048 * 64;
    const bf16_t* Vh = Vt + (size_t)bh * 64 * 2048;
    const float* bih = biasbuf + (size_t)bh * 2048;

    int fb0 = w * 2048, fb1 = fb0 + 1024;
    int f0 = fb0 + lane * 16, f1 = fb1 + lane * 16;
    int krow0 = f0 >> 7, kch0 = ((f0 >> 4) & 7) ^ (krow0 & 7);
    int krow1 = f1 >> 7, kch1 = ((f1 >> 4) & 7) ^ (krow1 & 7);

    bf16x8 qf[2][2];
#pragma unroll
    for (int qt = 0; qt < 2; ++qt)
#pragma unroll
        for (int dh = 0; dh < 2; ++dh)
            qf[qt][dh] = *(const bf16x8*)(Qh + (size_t)(qa + qt * 16 + l16) * 64 + dh * 32 + quad * 8);

    f32x4 o[2][4] = {};
    f32x4 lacc[2] = {};
    bf16x8 onesb;
#pragma unroll
    for (int i = 0; i < 8; ++i) onesb[i] = (bf16_t)1.0f;
    int swl = l16 & 7;
    int qh = quad >> 1, ql = quad & 1;

    {
        glds16(Kh + (size_t)krow0 * 64 + kch0 * 8, &kbuf[0][fb0 >> 1]);
        glds16(Kh + (size_t)krow1 * 64 + kch1 * 8, &kbuf[0][fb1 >> 1]);
        glds16(Vh + (size_t)krow0 * 2048 + kch0 * 8, &vbuf[0][fb0 >> 1]);
        glds16(Vh + (size_t)krow1 * 2048 + kch1 * 8, &vbuf[0][fb1 >> 1]);
    }

    for (int it = 0; it < 32; ++it) {
        int j0 = it * 64, sel = it & 1;
        __syncthreads();
        if (it + 1 < 32) {
            int jn = j0 + 64, sn = sel ^ 1;
            glds16(Kh + (size_t)(jn + krow0) * 64 + kch0 * 8, &kbuf[sn][fb0 >> 1]);
            glds16(Kh + (size_t)(jn + krow1) * 64 + kch1 * 8, &kbuf[sn][fb1 >> 1]);
            glds16(Vh + (size_t)krow0 * 2048 + jn + kch0 * 8, &vbuf[sn][fb0 >> 1]);
            glds16(Vh + (size_t)krow1 * 2048 + jn + kch1 * 8, &vbuf[sn][fb1 >> 1]);
        }
        const bf16_t* kb = kbuf[sel];
        const bf16_t* vb = vbuf[sel];

        // issue bias loads early (L2-resident, latency hides under QK^T)
        float4 b4[4];
#pragma unroll
        for (int kt = 0; kt < 4; ++kt)
            b4[kt] = *(const float4*)(bih + j0 + kt * 16 + quad * 4);

        f32x4 s[2][4];
#pragma unroll
        for (int kt = 0; kt < 4; ++kt) {
            f32x4 bi = { b4[kt].x, b4[kt].y, b4[kt].z, b4[kt].w };
            bf16x8 kf0 = *(const bf16x8*)(kb + (kt * 16 + l16) * 64 + ((quad ^ swl) * 8));
            bf16x8 kf1 = *(const bf16x8*)(kb + (kt * 16 + l16) * 64 + (((4 + quad) ^ swl) * 8));
#pragma unroll
            for (int qt = 0; qt < 2; ++qt) {
                s[qt][kt] = MFMA16(kf0, qf[qt][0], bi);
                s[qt][kt] = MFMA16(kf1, qf[qt][1], s[qt][kt]);
            }
        }

        bf16x8 pf[2][2];
#pragma unroll
        for (int qt = 0; qt < 2; ++qt) {
#pragma unroll
            for (int kt = 0; kt < 4; ++kt)
#pragma unroll
                for (int r = 0; r < 4; ++r)
                    s[qt][kt][r] = __builtin_amdgcn_exp2f(s[qt][kt][r]);
#pragma unroll
            for (int pv = 0; pv < 2; ++pv) {
                bf16x8 tmp;
#pragma unroll
                for (int i = 0; i < 4; ++i) {
                    tmp[i]     = (bf16_t)s[qt][2 * pv][i];
                    tmp[i + 4] = (bf16_t)s[qt][2 * pv + 1][i];
                }
                pf[qt][pv] = tmp;
            }
            lacc[qt] = MFMA16(pf[qt][0], onesb, lacc[qt]);
            lacc[qt] = MFMA16(pf[qt][1], onesb, lacc[qt]);
        }

#pragma unroll
        for (int dt = 0; dt < 4; ++dt) {
            const bf16_t* vrow = vb + (dt * 16 + l16) * 64 + ql * 4;
#pragma unroll
            for (int pv = 0; pv < 2; ++pv) {
                int c0 = (pv * 4 + qh) ^ swl;
                int c1 = (pv * 4 + 2 + qh) ^ swl;
                bf16x4 va = *(const bf16x4*)(vrow + c0 * 8);
                bf16x4 vc = *(const bf16x4*)(vrow + c1 * 8);
                bf16x8 vf = __builtin_shufflevector(va, vc, 0, 1, 2, 3, 4, 5, 6, 7);
#pragma unroll
                for (int qt = 0; qt < 2; ++qt)
                    o[qt][dt] = MFMA16(pf[qt][pv], vf, o[qt][dt]);
            }
        }
    }

#pragma unroll
    for (int qt = 0; qt < 2; ++qt) {
        f32x4 rinv;
#pragma unroll
        for (int r = 0; r < 4; ++r) rinv[r] = 1.0f / lacc[qt][r];
#pragma unroll
        for (int dt = 0; dt < 4; ++dt)
#pragma unroll
            for (int r = 0; r < 4; ++r) {
                int row = qa + qt * 16 + quad * 4 + r;
                O[(size_t)(b * 2048 + row) * 1024 + h * 64 + dt * 16 + l16] =
                    (bf16_t)(o[qt][dt][r] * rinv[r]);
            }
    }
}

// ---------------------------------------------------------------------------
__global__ __launch_bounds__(256) void out_gemm(const bf16_t* __restrict__ A,
                                                const bf16_t* __restrict__ Wt,
                                                const float* __restrict__ bias,
                                                float* __restrict__ Cout) {
    __shared__ __align__(16) bf16_t At[128 * 32];
    __shared__ __align__(16) bf16_t Bt[128 * 32];
    int t = threadIdx.x, w = t >> 6, lane = t & 63;
    int l16 = lane & 15, quad = lane >> 4;
    int wm = w & 1, wx = w >> 1;
    int m0 = blockIdx.x * 128;
    int n0 = blockIdx.y * 128;
    f32x4 acc[4][4] = {};
    int sw = (l16 >> 2) & 3;

    for (int k0 = 0; k0 < 1024; k0 += 32) {
#pragma unroll
        for (int i = 0; i < 2; ++i) {
            int fb = i * 4096 + w * 1024;
            int f = fb + lane * 16;
            int row = f >> 6;
            int ch = (f >> 4) & 3;
            int sc = ch ^ ((row >> 2) & 3);
            glds16(Wt + (size_t)(n0 + row) * 1024 + k0 + sc * 8, At + (fb >> 1));
            glds16(A + (size_t)(m0 + row) * 1024 + k0 + sc * 8, Bt + (fb >> 1));
        }
        __syncthreads();
        bf16x8 afr[4], bfr[4];
#pragma unroll
        for (int mi = 0; mi < 4; ++mi)
            afr[mi] = *(const bf16x8*)(At + (wm * 64 + mi * 16 + l16) * 32 + ((quad ^ sw) * 8));
#pragma unroll
        for (int ni = 0; ni < 4; ++ni)
            bfr[ni] = *(const bf16x8*)(Bt + (wx * 64 + ni * 16 + l16) * 32 + ((quad ^ sw) * 8));
#pragma unroll
        for (int mi = 0; mi < 4; ++mi)
#pragma unroll
            for (int ni = 0; ni < 4; ++ni)
                acc[mi][ni] = MFMA16(afr[mi], bfr[ni], acc[mi][ni]);
        __syncthreads();
    }

#pragma unroll
    for (int mi = 0; mi < 4; ++mi) {
        int gc = n0 + wm * 64 + mi * 16 + quad * 4;
        float4 bv = *(const float4*)(bias + gc);
#pragma unroll
        for (int ni = 0; ni < 4; ++ni) {
            int gx = m0 + wx * 64 + ni * 16 + l16;
            float4 ov = { acc[mi][ni][0] + bv.x, acc[mi][ni][1] + bv.y,
                          acc[mi][ni][2] + bv.z, acc[mi][ni][3] + bv.w };
            *(float4*)(Cout + (size_t)gx * 1024 + gc) = ov;
        }
    }
}

// ---------------------------------------------------------------------------
extern "C" void kernel_launch(void* const* d_in, const int* in_sizes, int n_in,
                              void* d_out, int out_size, void* d_ws, size_t ws_size,
                              hipStream_t stream) {
    const float* x     = (const float*)d_in[0];
    const float* cov   = (const float*)d_in[1];
    const float* w_qkv = (const float*)d_in[2];
    const float* w_out = (const float*)d_in[3];
    const float* b_out = (const float*)d_in[4];
    const float* w_ce1 = (const float*)d_in[5];
    const float* b_ce1 = (const float*)d_in[6];
    const float* w_ce2 = (const float*)d_in[7];
    const float* b_ce2 = (const float*)d_in[8];
    const float* w_fg1 = (const float*)d_in[9];
    const float* b_fg1 = (const float*)d_in[10];
    const float* w_fg2 = (const float*)d_in[11];
    const float* b_fg2 = (const float*)d_in[12];

    char* ws = (char*)d_ws;
    bf16_t* Wt     = (bf16_t*)(ws);              // 3072x1024
    bf16_t* WoT    = (bf16_t*)(ws + 6291456);    // 1024x1024
    bf16_t* Xb     = (bf16_t*)(ws + 8388608);    // 4096x1024
    bf16_t* Qb     = (bf16_t*)(ws + 16777216);   // (2,16,2048,64)
    bf16_t* Kbb    = (bf16_t*)(ws + 25165824);   // (2,16,2048,64)
    bf16_t* Vt     = (bf16_t*)(ws + 33554432);   // (2,16,64,2048)
    bf16_t* Ob     = (bf16_t*)(ws + 41943040);   // (4096,1024)
    float*  pooled = (float*)(ws + 50331648);    // 2x1024 f32
    float*  hacc   = (float*)(ws + 50339840);    // 2 f32
    float*  biasb  = (float*)(ws + 50340096);    // 2x16x2048 f32

    hipMemsetAsync(pooled, 0, 2 * 1024 * sizeof(float), stream);
    hipMemsetAsync(hacc, 0, 2 * sizeof(float), stream);
    f2b<<<4096, 256, 0, stream>>>(x, Xb);
    tr64<<<dim3(48, 16), 256, 0, stream>>>(w_qkv, Wt, 1024, 3072);
    tr64<<<dim3(16, 16), 256, 0, stream>>>(w_out, WoT, 1024, 1024);
    pool_partial<<<256, 256, 0, stream>>>(x, pooled);
    gate1<<<512, 256, 0, stream>>>(pooled, w_fg1, b_fg1, w_fg2, hacc);
    covbias_k<<<256, 256, 0, stream>>>(cov, w_ce1, b_ce1, w_ce2, b_ce2, hacc, b_fg2, biasb);
    qkv_gemm<<<dim3(32, 24), 256, 0, stream>>>(Xb, Wt, Qb, Kbb, Vt);
    attn_k<<<dim3(16, 32), 256, 0, stream>>>(Qb, Kbb, Vt, biasb, Ob);
    out_gemm<<<dim3(32, 8), 256, 0, stream>>>(Ob, WoT, b_out, (float*)d_out);
}

// Round 2
// 261.617 us; speedup vs baseline: 1.0658x; 1.0284x over previous
//
#include <hip/hip_runtime.h>
#include <math.h>

typedef __bf16 bf16_t;
typedef __bf16 bf16x8 __attribute__((ext_vector_type(8)));
typedef __bf16 bf16x4 __attribute__((ext_vector_type(4)));
typedef float f32x4 __attribute__((ext_vector_type(4)));

#define MFMA16(a, b, c) __builtin_amdgcn_mfma_f32_16x16x32_bf16((a), (b), (c), 0, 0, 0)

constexpr int Bc = 2, Nc = 2048, Dc = 1024, Hc = 16, HDc = 64;
constexpr float C1 = 0.18033688011112042f;     // 0.125 * log2(e), folded into Q at qkv epilogue
constexpr float LOG2E = 1.4426950408889634f;

// async global->LDS, 16B per lane; LDS base must be wave-uniform (HW adds lane*16)
__device__ __forceinline__ void glds16(const bf16_t* g, bf16_t* l) {
    __builtin_amdgcn_global_load_lds(
        (const __attribute__((address_space(1))) unsigned int*)g,
        (__attribute__((address_space(3))) unsigned int*)l, 16, 0, 0);
}

// async global->LDS, 4B per lane (HW adds lane*4); global src per-lane
__device__ __forceinline__ void glds4(const float* g, float* l) {
    __builtin_amdgcn_global_load_lds(
        (const __attribute__((address_space(1))) unsigned int*)g,
        (__attribute__((address_space(3))) unsigned int*)l, 4, 0, 0);
}

// ---------------------------------------------------------------------------
__global__ __launch_bounds__(256) void f2b(const float* __restrict__ src,
                                           bf16_t* __restrict__ dst) {
    int i = (blockIdx.x * 256 + threadIdx.x) * 4;
    float4 v = *(const float4*)(src + i);
    bf16x4 o = { (bf16_t)v.x, (bf16_t)v.y, (bf16_t)v.z, (bf16_t)v.w };
    *(bf16x4*)(dst + i) = o;
}

// ---------------------------------------------------------------------------
__global__ __launch_bounds__(256) void tr64(const float* __restrict__ src,
                                            bf16_t* __restrict__ dst, int R, int C) {
    __shared__ bf16_t tile[64 * 66];
    int r0 = blockIdx.y * 64, c0 = blockIdx.x * 64;
    int t = threadIdx.x;
    int cl = t & 63, rl = t >> 6;
#pragma unroll
    for (int p = 0; p < 16; ++p) {
        int r = p * 4 + rl;
        tile[r * 66 + cl] = (bf16_t)src[(size_t)(r0 + r) * C + c0 + cl];
    }
    __syncthreads();
#pragma unroll
    for (int p = 0; p < 16; ++p) {
        int r = p * 4 + rl;
        dst[(size_t)(c0 + r) * R + r0 + cl] = tile[cl * 66 + r];
    }
}

// ---------------------------------------------------------------------------
// 256 blocks: b = blk>>7, 16 rows per block
__global__ __launch_bounds__(256) void pool_partial(const float* __restrict__ x,
                                                    float* __restrict__ pooled) {
    int blk = blockIdx.x;
    int b = blk >> 7, ch = blk & 127;
    int t = threadIdx.x;
    int c = t * 4;
    float s0 = 0.f, s1 = 0.f, s2 = 0.f, s3 = 0.f;
    for (int rr = 0; rr < 16; ++rr) {
        float4 v = *(const float4*)(x + (size_t)(b * Nc + ch * 16 + rr) * Dc + c);
        s0 += v.x; s1 += v.y; s2 += v.z; s3 += v.w;
    }
    atomicAdd(&pooled[b * Dc + c + 0], s0);
    atomicAdd(&pooled[b * Dc + c + 1], s1);
    atomicAdd(&pooled[b * Dc + c + 2], s2);
    atomicAdd(&pooled[b * Dc + c + 3], s3);
}

// ---------------------------------------------------------------------------
// Gate MLP stage 1, parallel: one block per (b, j). hacc[b] += silu(h_j)*w_fg2[j]
__global__ __launch_bounds__(256) void gate1(const float* __restrict__ pooled,
                                             const float* __restrict__ w_fg1,
                                             const float* __restrict__ b_fg1,
                                             const float* __restrict__ w_fg2,
                                             float* __restrict__ hacc) {
    int b = blockIdx.x >> 8, j = blockIdx.x & 255;
    int t = threadIdx.x;
    float p = 0.f;
#pragma unroll
    for (int i = 0; i < 4; ++i) {
        int d = t * 4 + i;
        p += pooled[b * 1024 + d] * w_fg1[d * 256 + j];
    }
#pragma unroll
    for (int off = 32; off > 0; off >>= 1) p += __shfl_down(p, off);
    __shared__ float red[4];
    if ((t & 63) == 0) red[t >> 6] = p;
    __syncthreads();
    if (t == 0) {
        float hj = (red[0] + red[1] + red[2] + red[3]) * (1.0f / 2048.0f) + b_fg1[j];
        hj = hj / (1.0f + __expf(-hj)); // silu
        atomicAdd(&hacc[b], hj * w_fg2[j]);
    }
}

// ---------------------------------------------------------------------------
// biasbuf[b][h][n] = log2(e) * sigmoid(hacc[b]+b_fg2) * (silu(cov*w_ce1+b_ce1) @ w_ce2 + b_ce2)
__global__ __launch_bounds__(256) void covbias_k(const float* __restrict__ coverage,
                                                 const float* __restrict__ w_ce1,
                                                 const float* __restrict__ b_ce1,
                                                 const float* __restrict__ w_ce2,
                                                 const float* __restrict__ b_ce2,
                                                 const float* __restrict__ hacc,
                                                 const float* __restrict__ b_fg2,
                                                 float* __restrict__ biasbuf) {
    int t = threadIdx.x;
    int h = t & 15;
    int gn = blockIdx.x * 16 + (t >> 4);
    int b = gn >> 11, n = gn & 2047;
    float g = 1.0f / (1.0f + __expf(-(hacc[b] + b_fg2[0])));
    float c = coverage[gn];
    float acc = b_ce2[h];
    for (int j = 0; j < 256; ++j) {
        float tv = c * w_ce1[j] + b_ce1[j];
        tv = tv / (1.0f + __expf(-tv));
        acc += tv * w_ce2[j * 16 + h];
    }
    biasbuf[((size_t)b * 16 + h) * 2048 + n] = LOG2E * g * acc;
}

// ---------------------------------------------------------------------------
// QKV GEMM, transposed orientation: D[m=ncol][n=xrow] = Wt-row . X-row.
// Q gets pre-scaled by C1 = 0.125*log2(e) so attn can use exp2 with no FMA.
__global__ __launch_bounds__(256) void qkv_gemm(const bf16_t* __restrict__ Xb,
                                                const bf16_t* __restrict__ Wt,
                                                bf16_t* __restrict__ Q,
                                                bf16_t* __restrict__ Kb,
                                                bf16_t* __restrict__ Vt) {
    __shared__ __align__(16) bf16_t At[128 * 32];
    __shared__ __align__(16) bf16_t Bt[128 * 32];
    int t = threadIdx.x, w = t >> 6, lane = t & 63;
    int l16 = lane & 15, quad = lane >> 4;
    int wm = w & 1, wx = w >> 1;
    int m0 = blockIdx.x * 128;
    int n0 = blockIdx.y * 128;
    f32x4 acc[4][4] = {};
    int sw = (l16 >> 2) & 3;

    for (int k0 = 0; k0 < 1024; k0 += 32) {
#pragma unroll
        for (int i = 0; i < 2; ++i) {
            int fb = i * 4096 + w * 1024;
            int f = fb + lane * 16;
            int row = f >> 6;
            int ch = (f >> 4) & 3;
            int sc = ch ^ ((row >> 2) & 3);
            glds16(Wt + (size_t)(n0 + row) * 1024 + k0 + sc * 8, At + (fb >> 1));
            glds16(Xb + (size_t)(m0 + row) * 1024 + k0 + sc * 8, Bt + (fb >> 1));
        }
        __syncthreads();
        bf16x8 afr[4], bfr[4];
#pragma unroll
        for (int mi = 0; mi < 4; ++mi)
            afr[mi] = *(const bf16x8*)(At + (wm * 64 + mi * 16 + l16) * 32 + ((quad ^ sw) * 8));
#pragma unroll
        for (int ni = 0; ni < 4; ++ni)
            bfr[ni] = *(const bf16x8*)(Bt + (wx * 64 + ni * 16 + l16) * 32 + ((quad ^ sw) * 8));
#pragma unroll
        for (int mi = 0; mi < 4; ++mi)
#pragma unroll
            for (int ni = 0; ni < 4; ++ni)
                acc[mi][ni] = MFMA16(afr[mi], bfr[ni], acc[mi][ni]);
        __syncthreads();
    }

    int sec = n0 >> 10;
    float scq = (sec == 0) ? C1 : 1.0f;
#pragma unroll
    for (int mi = 0; mi < 4; ++mi) {
        int gc = n0 + wm * 64 + mi * 16 + quad * 4;
        int dcol = gc & 1023;
        int h = dcol >> 6, hd = dcol & 63;
#pragma unroll
        for (int ni = 0; ni < 4; ++ni) {
            int gx = m0 + wx * 64 + ni * 16 + l16;
            int b = gx >> 11, n = gx & 2047;
            size_t bh = (size_t)(b * 16 + h);
            if (sec == 2) {
#pragma unroll
                for (int r = 0; r < 4; ++r)
                    Vt[(bh * 64 + hd + r) * 2048 + n] = (bf16_t)acc[mi][ni][r];
            } else {
                bf16x4 pk = { (bf16_t)(acc[mi][ni][0] * scq), (bf16_t)(acc[mi][ni][1] * scq),
                              (bf16_t)(acc[mi][ni][2] * scq), (bf16_t)(acc[mi][ni][3] * scq) };
                bf16_t* dst = (sec == 0 ? Q : Kb);
                *(bf16x4*)(dst + (bh * 2048 + n) * 64 + hd) = pk;
            }
        }
    }
}

// ---------------------------------------------------------------------------
// Flash attention v5: 4 waves x 32 q, counted-vmcnt pipeline (T4) + setprio (T5).
//  - two raw s_barriers per tile; prefetch glds stay in flight across them
//    (vmcnt(5) waits only on loads issued a full iteration ago).
//  - bias staged via width-4 global_load_lds into LDS so the compute phase has
//    NO vmem ops (a global bias load would force the compiler to drain vmcnt).
__global__ __launch_bounds__(256) void attn_k(const bf16_t* __restrict__ Q,
                                              const bf16_t* __restrict__ Kb,
                                              const bf16_t* __restrict__ Vt,
                                              const float* __restrict__ biasbuf,
                                              bf16_t* __restrict__ O) {
    __shared__ __align__(16) bf16_t kbuf[2][64 * 64];
    __shared__ __align__(16) bf16_t vbuf[2][64 * 64];
    __shared__ __align__(16) float bbias[2][64];
    int t = threadIdx.x, w = t >> 6, lane = t & 63;
    int l16 = lane & 15, quad = lane >> 4;
    int bh = blockIdx.y;
    int b = bh >> 4, h = bh & 15;
    int qa = blockIdx.x * 128 + w * 32;
    const bf16_t* Qh = Q + (size_t)bh * 2048 * 64;
    const bf16_t* Kh = Kb + (size_t)bh * 2048 * 64;
    const bf16_t* Vh = Vt + (size_t)bh * 64 * 2048;
    const float* bih = biasbuf + (size_t)bh * 2048;

    int fb0 = w * 2048, fb1 = fb0 + 1024;
    int f0 = fb0 + lane * 16, f1 = fb1 + lane * 16;
    int krow0 = f0 >> 7, kch0 = ((f0 >> 4) & 7) ^ (krow0 & 7);
    int krow1 = f1 >> 7, kch1 = ((f1 >> 4) & 7) ^ (krow1 & 7);

    bf16x8 qf[2][2];
#pragma unroll
    for (int qt = 0; qt < 2; ++qt)
#pragma unroll
        for (int dh = 0; dh < 2; ++dh)
            qf[qt][dh] = *(const bf16x8*)(Qh + (size_t)(qa + qt * 16 + l16) * 64 + dh * 32 + quad * 8);

    f32x4 o[2][4] = {};
    f32x4 lacc[2] = {};
    bf16x8 onesb;
#pragma unroll
    for (int i = 0; i < 8; ++i) onesb[i] = (bf16_t)1.0f;
    int swl = l16 & 7;
    int qh = quad >> 1, ql = quad & 1;

    // stage tile 'tile' into buffer 'bf' (5 vmem ops per wave: K2 + V2 + bias1)
    auto stage = [&](int tile, int bf) {
        int jn = tile * 64;
        glds16(Kh + (size_t)(jn + krow0) * 64 + kch0 * 8, &kbuf[bf][fb0 >> 1]);
        glds16(Kh + (size_t)(jn + krow1) * 64 + kch1 * 8, &kbuf[bf][fb1 >> 1]);
        glds16(Vh + (size_t)krow0 * 2048 + jn + kch0 * 8, &vbuf[bf][fb0 >> 1]);
        glds16(Vh + (size_t)krow1 * 2048 + jn + kch1 * 8, &vbuf[bf][fb1 >> 1]);
        glds4(bih + jn + lane, &bbias[bf][0]);   // 64 lanes x 4B = 64 floats
    };

    stage(0, 0);   // outstanding: 5

    for (int it = 0; it < 32; ++it) {
        int sel = it & 1;
        // all my LDS reads of buf[sel^1] (prev tile) complete
        asm volatile("s_waitcnt lgkmcnt(0)" ::: "memory");
        __builtin_amdgcn_s_barrier();            // everyone done reading buf[sel^1]
        if (it + 1 < 32) {
            stage(it + 1, sel ^ 1);              // outstanding: 10
            asm volatile("s_waitcnt vmcnt(5)" ::: "memory");   // tile-it loads done
        } else {
            asm volatile("s_waitcnt vmcnt(0)" ::: "memory");
        }
        __builtin_amdgcn_s_barrier();            // everyone's tile-it data in LDS
        __builtin_amdgcn_sched_barrier(0);

        const bf16_t* kb = kbuf[sel];
        const bf16_t* vb = vbuf[sel];
        const float* bp = bbias[sel];

        f32x4 s[2][4];
        __builtin_amdgcn_s_setprio(1);
#pragma unroll
        for (int kt = 0; kt < 4; ++kt) {
            f32x4 bi = *(const f32x4*)(bp + kt * 16 + quad * 4);   // LDS broadcast
            bf16x8 kf0 = *(const bf16x8*)(kb + (kt * 16 + l16) * 64 + ((quad ^ swl) * 8));
            bf16x8 kf1 = *(const bf16x8*)(kb + (kt * 16 + l16) * 64 + (((4 + quad) ^ swl) * 8));
#pragma unroll
            for (int qt = 0; qt < 2; ++qt) {
                s[qt][kt] = MFMA16(kf0, qf[qt][0], bi);
                s[qt][kt] = MFMA16(kf1, qf[qt][1], s[qt][kt]);
            }
        }
        __builtin_amdgcn_s_setprio(0);

        bf16x8 pf[2][2];
#pragma unroll
        for (int qt = 0; qt < 2; ++qt) {
#pragma unroll
            for (int kt = 0; kt < 4; ++kt)
#pragma unroll
                for (int r = 0; r < 4; ++r)
                    s[qt][kt][r] = __builtin_amdgcn_exp2f(s[qt][kt][r]);
#pragma unroll
            for (int pv = 0; pv < 2; ++pv) {
                bf16x8 tmp;
#pragma unroll
                for (int i = 0; i < 4; ++i) {
                    tmp[i]     = (bf16_t)s[qt][2 * pv][i];
                    tmp[i + 4] = (bf16_t)s[qt][2 * pv + 1][i];
                }
                pf[qt][pv] = tmp;
            }
        }

        __builtin_amdgcn_s_setprio(1);
#pragma unroll
        for (int qt = 0; qt < 2; ++qt) {
            lacc[qt] = MFMA16(pf[qt][0], onesb, lacc[qt]);
            lacc[qt] = MFMA16(pf[qt][1], onesb, lacc[qt]);
        }
#pragma unroll
        for (int dt = 0; dt < 4; ++dt) {
            const bf16_t* vrow = vb + (dt * 16 + l16) * 64 + ql * 4;
#pragma unroll
            for (int pv = 0; pv < 2; ++pv) {
                int c0 = (pv * 4 + qh) ^ swl;
                int c1 = (pv * 4 + 2 + qh) ^ swl;
                bf16x4 va = *(const bf16x4*)(vrow + c0 * 8);
                bf16x4 vc = *(const bf16x4*)(vrow + c1 * 8);
                bf16x8 vf = __builtin_shufflevector(va, vc, 0, 1, 2, 3, 4, 5, 6, 7);
#pragma unroll
                for (int qt = 0; qt < 2; ++qt)
                    o[qt][dt] = MFMA16(pf[qt][pv], vf, o[qt][dt]);
            }
        }
        __builtin_amdgcn_s_setprio(0);
    }

#pragma unroll
    for (int qt = 0; qt < 2; ++qt) {
        f32x4 rinv;
#pragma unroll
        for (int r = 0; r < 4; ++r) rinv[r] = 1.0f / lacc[qt][r];
#pragma unroll
        for (int dt = 0; dt < 4; ++dt)
#pragma unroll
            for (int r = 0; r < 4; ++r) {
                int row = qa + qt * 16 + quad * 4 + r;
                O[(size_t)(b * 2048 + row) * 1024 + h * 64 + dt * 16 + l16] =
                    (bf16_t)(o[qt][dt][r] * rinv[r]);
            }
    }
}

// ---------------------------------------------------------------------------
__global__ __launch_bounds__(256) void out_gemm(const bf16_t* __restrict__ A,
                                                const bf16_t* __restrict__ Wt,
                                                const float* __restrict__ bias,
                                                float* __restrict__ Cout) {
    __shared__ __align__(16) bf16_t At[128 * 32];
    __shared__ __align__(16) bf16_t Bt[128 * 32];
    int t = threadIdx.x, w = t >> 6, lane = t & 63;
    int l16 = lane & 15, quad = lane >> 4;
    int wm = w & 1, wx = w >> 1;
    int m0 = blockIdx.x * 128;
    int n0 = blockIdx.y * 128;
    f32x4 acc[4][4] = {};
    int sw = (l16 >> 2) & 3;

    for (int k0 = 0; k0 < 1024; k0 += 32) {
#pragma unroll
        for (int i = 0; i < 2; ++i) {
            int fb = i * 4096 + w * 1024;
            int f = fb + lane * 16;
            int row = f >> 6;
            int ch = (f >> 4) & 3;
            int sc = ch ^ ((row >> 2) & 3);
            glds16(Wt + (size_t)(n0 + row) * 1024 + k0 + sc * 8, At + (fb >> 1));
            glds16(A + (size_t)(m0 + row) * 1024 + k0 + sc * 8, Bt + (fb >> 1));
        }
        __syncthreads();
        bf16x8 afr[4], bfr[4];
#pragma unroll
        for (int mi = 0; mi < 4; ++mi)
            afr[mi] = *(const bf16x8*)(At + (wm * 64 + mi * 16 + l16) * 32 + ((quad ^ sw) * 8));
#pragma unroll
        for (int ni = 0; ni < 4; ++ni)
            bfr[ni] = *(const bf16x8*)(Bt + (wx * 64 + ni * 16 + l16) * 32 + ((quad ^ sw) * 8));
#pragma unroll
        for (int mi = 0; mi < 4; ++mi)
#pragma unroll
            for (int ni = 0; ni < 4; ++ni)
                acc[mi][ni] = MFMA16(afr[mi], bfr[ni], acc[mi][ni]);
        __syncthreads();
    }

#pragma unroll
    for (int mi = 0; mi < 4; ++mi) {
        int gc = n0 + wm * 64 + mi * 16 + quad * 4;
        float4 bv = *(const float4*)(bias + gc);
#pragma unroll
        for (int ni = 0; ni < 4; ++ni) {
            int gx = m0 + wx * 64 + ni * 16 + l16;
            float4 ov = { acc[mi][ni][0] + bv.x, acc[mi][ni][1] + bv.y,
                          acc[mi][ni][2] + bv.z, acc[mi][ni][3] + bv.w };
            *(float4*)(Cout + (size_t)gx * 1024 + gc) = ov;
        }
    }
}

// ---------------------------------------------------------------------------
extern "C" void kernel_launch(void* const* d_in, const int* in_sizes, int n_in,
                              void* d_out, int out_size, void* d_ws, size_t ws_size,
                              hipStream_t stream) {
    const float* x     = (const float*)d_in[0];
    const float* cov   = (const float*)d_in[1];
    const float* w_qkv = (const float*)d_in[2];
    const float* w_out = (const float*)d_in[3];
    const float* b_out = (const float*)d_in[4];
    const float* w_ce1 = (const float*)d_in[5];
    const float* b_ce1 = (const float*)d_in[6];
    const float* w_ce2 = (const float*)d_in[7];
    const float* b_ce2 = (const float*)d_in[8];
    const float* w_fg1 = (const float*)d_in[9];
    const float* b_fg1 = (const float*)d_in[10];
    const float* w_fg2 = (const float*)d_in[11];
    const float* b_fg2 = (const float*)d_in[12];

    char* ws = (char*)d_ws;
    bf16_t* Wt     = (bf16_t*)(ws);              // 3072x1024
    bf16_t* WoT    = (bf16_t*)(ws + 6291456);    // 1024x1024
    bf16_t* Xb     = (bf16_t*)(ws + 8388608);    // 4096x1024
    bf16_t* Qb     = (bf16_t*)(ws + 16777216);   // (2,16,2048,64)
    bf16_t* Kbb    = (bf16_t*)(ws + 25165824);   // (2,16,2048,64)
    bf16_t* Vt     = (bf16_t*)(ws + 33554432);   // (2,16,64,2048)
    bf16_t* Ob     = (bf16_t*)(ws + 41943040);   // (4096,1024)
    float*  pooled = (float*)(ws + 50331648);    // 2x1024 f32
    float*  hacc   = (float*)(ws + 50339840);    // 2 f32
    float*  biasb  = (float*)(ws + 50340096);    // 2x16x2048 f32

    hipMemsetAsync(pooled, 0, 2 * 1024 * sizeof(float), stream);
    hipMemsetAsync(hacc, 0, 2 * sizeof(float), stream);
    f2b<<<4096, 256, 0, stream>>>(x, Xb);
    tr64<<<dim3(48, 16), 256, 0, stream>>>(w_qkv, Wt, 1024, 3072);
    tr64<<<dim3(16, 16), 256, 0, stream>>>(w_out, WoT, 1024, 1024);
    pool_partial<<<256, 256, 0, stream>>>(x, pooled);
    gate1<<<512, 256, 0, stream>>>(pooled, w_fg1, b_fg1, w_fg2, hacc);
    covbias_k<<<256, 256, 0, stream>>>(cov, w_ce1, b_ce1, w_ce2, b_ce2, hacc, b_fg2, biasb);
    qkv_gemm<<<dim3(32, 24), 256, 0, stream>>>(Xb, Wt, Qb, Kbb, Vt);
    attn_k<<<dim3(16, 32), 256, 0, stream>>>(Qb, Kbb, Vt, biasb, Ob);
    out_gemm<<<dim3(32, 8), 256, 0, stream>>>(Ob, WoT, b_out, (float*)d_out);
}